// Round 3
// baseline (1088.250 us; speedup 1.0000x reference)
//
#include <hip/hip_runtime.h>
#include <hip/hip_bf16.h>

// channel_attention: einsum('bocs,bocm->bocs', x, softmax(score)) contracts m which
// only appears in score => multiplies x by softmax row-sum == 1 (within fp32 eps).
// So q/k/atten are dead code and the problem is exactly:
//   out[g,c,s] = LN_c( sum_m Wp[c][m] * x[g][m][s] + bp[c] ) * gp[c] + betap[c]
// g = b*o in [0,128). Per group: GEMM M=C=128, N=3000, K=128, + per-column LN.
//
// R3: latency-bound fix (R2: occupancy 21%, HBM 26%, nothing saturated).
//  - W read directly from global (32 KB bf16 == exactly L1-resident; shared by all
//    blocks). No W LDS, no W staging barrier.
//  - 64-col X tiles -> 16 KB LDS only -> 4 blocks/CU at launch_bounds(256,4).
//  - Wave owns 16 cols x 128 channels: acc = 32 VGPRs, 4 hoisted B-frags, LN in-wave.

#define C    128
#define SEQ  3000
#define NG   128
#define NT   64                        // columns per block
#define NBLK ((SEQ + NT - 1) / NT)     // 47

typedef float f4 __attribute__((ext_vector_type(4)));
typedef short short8 __attribute__((ext_vector_type(8)));

__device__ __forceinline__ unsigned short f2bf(float f) {
    union { float f; unsigned u; } v; v.f = f;
    unsigned r = v.u + 0x7fffu + ((v.u >> 16) & 1u);   // RNE
    return (unsigned short)(r >> 16);
}

// packed f32x2 -> bf16x2 (v_cvt_pk_bf16_f32 on gfx950 via HIP intrinsic)
__device__ __forceinline__ unsigned pk2bf(float lo, float hi) {
    __hip_bfloat162 h = __float22bfloat162_rn(float2{lo, hi});
    union { __hip_bfloat162 h; unsigned u; } v; v.h = h;
    return v.u;
}

// 16B-chunk XOR swizzle (R2-verified: SQ_LDS_BANK_CONFLICT == 0)
__device__ __forceinline__ int swz(int row, int chunk) {
    return chunk ^ ((row ^ (row >> 2)) & 15);
}

__global__ void cvt_wp(const float* __restrict__ Wp, unsigned short* __restrict__ out) {
    int i = blockIdx.x * 256 + threadIdx.x;
    if (i < C * C) out[i] = f2bf(Wp[i]);
}

__global__ __launch_bounds__(256, 4) void gemm_ln_mfma(
    const float* __restrict__ x,             // [NG][C][SEQ] fp32
    const unsigned short* __restrict__ wbf,  // [C][C] bf16 (c-major, m contiguous)
    const float* __restrict__ bp,
    const float* __restrict__ gp,
    const float* __restrict__ bep,
    float* __restrict__ out)                 // [NG][C][SEQ] fp32
{
    __shared__ __align__(16) unsigned short Xl[NT * C];  // 16 KB, [s][m] bf16 swizzled

    const int g  = blockIdx.y;
    const int s0 = blockIdx.x * NT;
    const float* xg = x + (size_t)g * (C * SEQ);
    float* og = out + (size_t)g * (C * SEQ);
    const int t = threadIdx.x;

    // ---- stage X transposed: thread owns (s-quad, m-chunk-of-8).
    // 8 coalesced f4 row loads -> in-register 8x4 transpose -> 4 ds_write_b128.
    {
        const int sq  = t & 15;              // s-quad (consecutive lanes -> coalesced)
        const int mc  = t >> 4;              // m-chunk 0..15
        const int s_loc  = 4 * sq;
        const int s_glob = s0 + s_loc;
        const bool valid = s_glob < SEQ;     // SEQ%4==0 -> quad wholly valid/invalid
        f4 r[8];
        const float* xp = xg + (size_t)(mc * 8) * SEQ + s_glob;
        #pragma unroll
        for (int rr = 0; rr < 8; ++rr) {
            if (valid) r[rr] = *(const f4*)(xp + (size_t)rr * SEQ);
            else       r[rr] = (f4){0.f, 0.f, 0.f, 0.f};
        }
        #pragma unroll
        for (int j = 0; j < 4; ++j) {
            const int sl = s_loc + j;
            uint4 pk;
            pk.x = pk2bf(r[0][j], r[1][j]);
            pk.y = pk2bf(r[2][j], r[3][j]);
            pk.z = pk2bf(r[4][j], r[5][j]);
            pk.w = pk2bf(r[6][j], r[7][j]);
            *(uint4*)&Xl[sl * C + swz(sl, mc) * 8] = pk;
        }
    }
    __syncthreads();

    // ---- MFMA: wave owns 16 cols x all 128 channels (LN fully in-wave)
    const int w    = t >> 6;
    const int lane = t & 63;
    const int col  = lane & 15;
    const int quad = lane >> 4;

    // hoist all 4 B-fragments (this wave's 16 columns, full K)
    short8 b[4];
    {
        const int srow = 16 * w + col;
        #pragma unroll
        for (int kc = 0; kc < 4; ++kc)
            b[kc] = *(const short8*)&Xl[srow * C + swz(srow, 4 * kc + quad) * 8];
    }

    f4 acc[8];   // 32 VGPRs
    #pragma unroll
    for (int mt = 0; mt < 8; ++mt) acc[mt] = (f4){0.f, 0.f, 0.f, 0.f};

    #pragma unroll
    for (int kc = 0; kc < 4; ++kc) {
        short8 a[8];
        #pragma unroll
        for (int mt = 0; mt < 8; ++mt)   // W from global: L1-resident (32 KB exactly)
            a[mt] = *(const short8*)(wbf + (16 * mt + col) * C + (4 * kc + quad) * 8);
        #pragma unroll
        for (int mt = 0; mt < 8; ++mt)
            acc[mt] = __builtin_amdgcn_mfma_f32_16x16x32_bf16(a[mt], b[kc], acc[mt], 0, 0, 0);
    }

    // ---- bias + in-wave per-column LayerNorm (rows of a column span the 4 quads)
    float s = 0.f, q = 0.f;
    #pragma unroll
    for (int mt = 0; mt < 8; ++mt) {
        const f4 b4 = *(const f4*)(bp + 16 * mt + 4 * quad);
        #pragma unroll
        for (int r = 0; r < 4; ++r) {
            float y = acc[mt][r] + b4[r];
            acc[mt][r] = y;
            s += y; q += y * y;
        }
    }
    s += __shfl_xor(s, 16); q += __shfl_xor(q, 16);
    s += __shfl_xor(s, 32); q += __shfl_xor(q, 32);
    const float mean = s * (1.0f / C);
    const float var  = q * (1.0f / C) - mean * mean;
    const float rstd = rsqrtf(var + 1e-5f);

    // ---- scale/shift + store
    const int sg = s0 + 16 * w + col;
    if (sg < SEQ) {
        #pragma unroll
        for (int mt = 0; mt < 8; ++mt) {
            const f4 g4 = *(const f4*)(gp  + 16 * mt + 4 * quad);
            const f4 e4 = *(const f4*)(bep + 16 * mt + 4 * quad);
            #pragma unroll
            for (int r = 0; r < 4; ++r) {
                const int c = 16 * mt + 4 * quad + r;
                og[(size_t)c * SEQ + sg] = (acc[mt][r] - mean) * rstd * g4[r] + e4[r];
            }
        }
    }
}

extern "C" void kernel_launch(void* const* d_in, const int* in_sizes, int n_in,
                              void* d_out, int out_size, void* d_ws, size_t ws_size,
                              hipStream_t stream) {
    // inputs: x, Wq, bq, gq, betaq, Wk, bk, gk, betak, Wp, bp, gp, betap
    const float* x   = (const float*)d_in[0];
    const float* Wp  = (const float*)d_in[9];
    const float* bp  = (const float*)d_in[10];
    const float* gp  = (const float*)d_in[11];
    const float* bep = (const float*)d_in[12];
    float* out = (float*)d_out;
    unsigned short* wbf = (unsigned short*)d_ws;   // 32 KB bf16 weights

    hipLaunchKernelGGL(cvt_wp, dim3(64), dim3(256), 0, stream, Wp, wbf);

    dim3 grid(NBLK, NG);
    hipLaunchKernelGGL(gemm_ln_mfma, grid, dim3(256), 0, stream,
                       x, wbf, bp, gp, bep, out);
}